// Round 12
// baseline (32.254 us; speedup 1.0000x reference)
//
#include <hip/hip_runtime.h>
#include <hip/hip_bf16.h>
#include <math.h>

// Problem constants: S=1000, C=100, L=50, B=20, K=64, N=16384
#define CC 100
#define LL 50
#define BB 20
#define KK 64

// ---------------------------------------------------------------------------
// Kernel 1: grid = CC blocks (one per course c), 256 threads (4 waves).
//   Q2[c,b] = (1 - sig(slide_[c]) - sig(guess_[c])) * sum_k Pm[k,c] * E[k,b]
//   G[c]   = sig(guess_[c])
// (unchanged from rounds 5-6 — measured minor)
// ---------------------------------------------------------------------------
__global__ __launch_bounds__(256) void compute_q_kernel(
    const float* __restrict__ P, const float* __restrict__ D,
    const float* __restrict__ P_A, const float* __restrict__ P_B,
    const float* __restrict__ P_C, const float* __restrict__ D_A,
    const float* __restrict__ D_B, const float* __restrict__ guess_,
    const float* __restrict__ slide_,
    float* __restrict__ Q2, float* __restrict__ G)
{
    const int c    = blockIdx.x;
    const int t    = threadIdx.x;
    const int w    = t >> 6;
    const int lane = t & 63;            // == k

    __shared__ float PCs[BB * BB];
    __shared__ float rowsum_sh[KK];

    if (t < (BB * BB) / 4) ((float4*)PCs)[t] = ((const float4*)P_C)[t];

    {
        const int k = t >> 2, q = t & 3;
        const float* __restrict__ pr  = P   + k * CC + q * 25;
        const float* __restrict__ par = P_A + k * CC + q * 25;
        const float* __restrict__ pbr = P_B + k * CC + q * 25;
        float s = 0.f;
        #pragma unroll
        for (int i = 0; i < 25; ++i) s += __expf(fmaf(pr[i], par[i], pbr[i]));
        s += __shfl_xor(s, 1);
        s += __shfl_xor(s, 2);
        if (q == 0) rowsum_sh[k] = s;
    }

    float dm[BB];
    {
        const float4* d4  = (const float4*)(D   + lane * BB);
        const float4* da4 = (const float4*)(D_A + lane * BB);
        const float4* db4 = (const float4*)(D_B + lane * BB);
        #pragma unroll
        for (int i = 0; i < 5; ++i) {
            const float4 dv = d4[i], av = da4[i], bv = db4[i];
            dm[4 * i + 0] = __expf(fmaf(dv.x, av.x, bv.x));
            dm[4 * i + 1] = __expf(fmaf(dv.y, av.y, bv.y));
            dm[4 * i + 2] = __expf(fmaf(dv.z, av.z, bv.z));
            dm[4 * i + 3] = __expf(fmaf(dv.w, av.w, bv.w));
        }
    }
    #pragma unroll
    for (int b = 0; b < BB; ++b) {
        float s = dm[b];
        s += __shfl_xor(s, 1);  s += __shfl_xor(s, 2);  s += __shfl_xor(s, 4);
        s += __shfl_xor(s, 8);  s += __shfl_xor(s, 16); s += __shfl_xor(s, 32);
        dm[b] *= (1.f / s);
    }
    __syncthreads();

    float ev[5];
    #pragma unroll
    for (int j = 0; j < 5; ++j) {
        const int b = 5 * w + j;
        float acc = 0.f;
        #pragma unroll
        for (int jj = 0; jj < BB; ++jj) acc = fmaf(dm[jj], PCs[jj * BB + b], acc);
        ev[j] = acc;
    }

    const float ps = fmaf(P[lane * CC + c], P_A[lane * CC + c], P_B[lane * CC + c]);
    const float pm = __expf(ps) / rowsum_sh[lane];

    float qv[5];
    #pragma unroll
    for (int j = 0; j < 5; ++j) {
        float v = pm * ev[j];
        v += __shfl_xor(v, 1);  v += __shfl_xor(v, 2);  v += __shfl_xor(v, 4);
        v += __shfl_xor(v, 8);  v += __shfl_xor(v, 16); v += __shfl_xor(v, 32);
        qv[j] = v;
    }
    if (lane == 0) {
        const float g  = 1.f / (1.f + __expf(-guess_[c]));
        const float sl = 1.f / (1.f + __expf(-slide_[c]));
        const float scale = 1.f - sl - g;
        #pragma unroll
        for (int j = 0; j < 5; ++j) Q2[c * BB + 5 * w + j] = qv[j] * scale;
        if (w == 0) G[c] = g;
    }
}

// ---------------------------------------------------------------------------
// Kernel 2: two samples per wave (r6 structure). SINGLE CHANGE: col-PAIR
// gather via float2 — lane = pair p (lane%10) + row-chunk g (lane/10, 6
// chunks of 9/9/8/8/8/8 rows). Halves gather VMEM instrs (34->18/wave),
// halves X-distribution shuffles, 100% line utilization per 80B row chunk.
// Combine: 3-step fold of the 6 row-chunk partials via absolute-lane shfl
// (+30, then +10/+20 reads). No LDS staging, no barriers.
// ---------------------------------------------------------------------------
__global__ __launch_bounds__(256) void main_kernel(
    const float* __restrict__ X, const int* __restrict__ stu,
    const int* __restrict__ cour, const float* __restrict__ csa,
    const float* __restrict__ Q2, const float* __restrict__ G,
    float* __restrict__ out, int N)
{
    const int t = threadIdx.x;
    const int w = t >> 6, lane = t & 63;
    const int n0 = blockIdx.x * 8 + 2 * w;
    const int n1 = n0 + 1;
    if (n0 >= N) return;
    const bool hasB = (n1 < N);

    const int sA = stu[n0], cA = cour[n0];
    const int sB = hasB ? stu[n1] : sA;
    const int cB = hasB ? cour[n1] : cA;
    const float* __restrict__ baseA = csa + ((size_t)sA * CC + cA) * (size_t)(LL * BB);
    const float* __restrict__ baseB = csa + ((size_t)sB * CC + cB) * (size_t)(LL * BB);

    const int p  = lane % 10;                 // column pair: cols (2p, 2p+1)
    const int g  = lane / 10;                 // row chunk 0..6 (g==6 inactive)
    const bool act = (g < 6);
    const int r0 = (g < 2) ? 9 * g : 8 * g + 2;   // chunk starts 0,9,18,26,34,42
    const bool has9 = (g < 2);                    // chunks 0,1 have 9 rows

    // --- Cold gather first: 8(+1) float2 per sample (8B-aligned). ---
    float2 va[9], vb[9];
    #pragma unroll
    for (int i = 0; i < 9; ++i) { va[i] = make_float2(0.f, 0.f); vb[i] = make_float2(0.f, 0.f); }
    if (act) {
        #pragma unroll
        for (int i = 0; i < 8; ++i)
            va[i] = *(const float2*)(baseA + (r0 + i) * BB + 2 * p);
        #pragma unroll
        for (int i = 0; i < 8; ++i)
            vb[i] = *(const float2*)(baseB + (r0 + i) * BB + 2 * p);
        if (has9) {
            va[8] = *(const float2*)(baseA + (r0 + 8) * BB + 2 * p);
            vb[8] = *(const float2*)(baseB + (r0 + 8) * BB + 2 * p);
        }
    }

    // X rows: one coalesced load each, distributed by shuffle.
    const float xvA = (lane < LL) ? X[(size_t)n0 * LL + lane] : 0.f;
    const float xvB = (hasB && lane < LL) ? X[(size_t)n1 * LL + lane] : 0.f;

    // Hot operands (L1/L2): Q2 rows + G, shared by both samples.
    const int c1ok = (lane < CC - 64);
    float4 q0[5], q1[5];
    {
        const float4* Q2v0 = (const float4*)(Q2 + lane * BB);
        #pragma unroll
        for (int k = 0; k < 5; ++k) q0[k] = Q2v0[k];
        if (c1ok) {
            const float4* Q2v1 = (const float4*)(Q2 + (64 + lane) * BB);
            #pragma unroll
            for (int k = 0; k < 5; ++k) q1[k] = Q2v1[k];
        }
    }
    const float g0v = G[lane];
    const float g1v = c1ok ? G[64 + lane] : 0.f;

    // --- Fused column softmax + X-weighted reduce, both cols of the pair. ---
    float ss0A = 0.f, ss1A = 0.f, ts0A = 0.f, ts1A = 0.f;
    float ss0B = 0.f, ss1B = 0.f, ts0B = 0.f, ts1B = 0.f;
    #pragma unroll
    for (int i = 0; i < 8; ++i) {
        const float xA = __shfl(xvA, r0 + i);
        const float xB = __shfl(xvB, r0 + i);
        const float e0A = __expf(va[i].x), e1A = __expf(va[i].y);
        const float e0B = __expf(vb[i].x), e1B = __expf(vb[i].y);
        ss0A += e0A; ss1A += e1A; ss0B += e0B; ss1B += e1B;
        ts0A = fmaf(e0A, xA, ts0A); ts1A = fmaf(e1A, xA, ts1A);
        ts0B = fmaf(e0B, xB, ts0B); ts1B = fmaf(e1B, xB, ts1B);
    }
    if (has9) {
        const float xA = __shfl(xvA, r0 + 8);
        const float xB = __shfl(xvB, r0 + 8);
        const float e0A = __expf(va[8].x), e1A = __expf(va[8].y);
        const float e0B = __expf(vb[8].x), e1B = __expf(vb[8].y);
        ss0A += e0A; ss1A += e1A; ss0B += e0B; ss1B += e1B;
        ts0A = fmaf(e0A, xA, ts0A); ts1A = fmaf(e1A, xA, ts1A);
        ts0B = fmaf(e0B, xB, ts0B); ts1B = fmaf(e1B, xB, ts1B);
    }
    // Inactive lanes (g==6) contribute zeros; lanes >=60 never feed g<3 folds.

    // --- Fold 6 row-chunk partials: q += shfl(q,+30); total = q + q(+10) + q(+20). ---
    #define FOLD(q, tot)                                        \
        {                                                       \
            q += __shfl(q, lane + 30);                          \
            const float _a = __shfl(q, lane + 10);              \
            const float _b = __shfl(q, lane + 20);              \
            tot = q + _a + _b; /* valid at lanes 0..9 (g==0) */ \
        }
    float S0A, S1A, T0A, T1A, S0B, S1B, T0B, T1B;
    FOLD(ss0A, S0A) FOLD(ss1A, S1A) FOLD(ts0A, T0A) FOLD(ts1A, T1A)
    FOLD(ss0B, S0B) FOLD(ss1B, S1B) FOLD(ts0B, T0B) FOLD(ts1B, T1B)
    #undef FOLD

    // Lane p<10 holds A for cols 2p (A0) and 2p+1 (A1), both samples.
    const float A0A = T0A / S0A, A1A = T1A / S1A;
    const float A0B = T0B / S0B, A1B = T1B / S1B;

    // Matvecs: out[n,c] = sum_b A[b]*Q2[c,b] + G[c]; A broadcast via readlane.
    float y0A = 0.f, y1A = 0.f, y0B = 0.f, y1B = 0.f;
    #pragma unroll
    for (int bb = 0; bb < BB; ++bb) {
        const int src = bb >> 1;
        const float aA = __uint_as_float(__builtin_amdgcn_readlane(
            __float_as_uint((bb & 1) ? A1A : A0A), src));
        const float aB = __uint_as_float(__builtin_amdgcn_readlane(
            __float_as_uint((bb & 1) ? A1B : A0B), src));
        const float qv0 = ((const float*)q0)[bb];
        const float qv1 = ((const float*)q1)[bb];
        y0A = fmaf(aA, qv0, y0A);  y1A = fmaf(aA, qv1, y1A);
        y0B = fmaf(aB, qv0, y0B);  y1B = fmaf(aB, qv1, y1B);
    }
    float* orowA = out + (size_t)n0 * CC;
    orowA[lane] = y0A + g0v;
    if (c1ok) orowA[64 + lane] = y1A + g1v;
    if (hasB) {
        float* orowB = out + (size_t)n1 * CC;
        orowB[lane] = y0B + g0v;
        if (c1ok) orowB[64 + lane] = y1B + g1v;
    }
}

extern "C" void kernel_launch(void* const* d_in, const int* in_sizes, int n_in,
                              void* d_out, int out_size, void* d_ws, size_t ws_size,
                              hipStream_t stream) {
    const float* X      = (const float*)d_in[0];
    const int*   stu    = (const int*)  d_in[1];
    const int*   cour   = (const int*)  d_in[2];
    const float* csa    = (const float*)d_in[3];
    const float* P      = (const float*)d_in[4];
    const float* D      = (const float*)d_in[5];
    const float* P_A    = (const float*)d_in[6];
    const float* P_B    = (const float*)d_in[7];
    const float* P_C    = (const float*)d_in[8];
    const float* D_A    = (const float*)d_in[9];
    const float* D_B    = (const float*)d_in[10];
    const float* guess_ = (const float*)d_in[11];
    const float* slide_ = (const float*)d_in[12];
    float* out = (float*)d_out;
    float* Q2  = (float*)d_ws;            // C*B floats
    float* G   = (float*)d_ws + CC * BB;  // C floats

    const int N = in_sizes[1];   // 16384

    compute_q_kernel<<<CC, 256, 0, stream>>>(P, D, P_A, P_B, P_C, D_A, D_B,
                                             guess_, slide_, Q2, G);
    main_kernel<<<(N + 7) / 8, 256, 0, stream>>>(X, stu, cour, csa, Q2, G, out, N);
}

// Round 13
// 31.436 us; speedup vs baseline: 1.0260x; 1.0260x over previous
//
#include <hip/hip_runtime.h>
#include <hip/hip_bf16.h>
#include <math.h>

// Problem constants: S=1000, C=100, L=50, B=20, K=64, N=16384
#define CC 100
#define LL 50
#define BB 20
#define KK 64

// ---------------------------------------------------------------------------
// Kernel 1: grid = CC blocks (one per course c), 256 threads (4 waves).
//   Q2[c,b] = (1 - sig(slide_[c]) - sig(guess_[c])) * sum_k Pm[k,c] * E[k,b]
//   G[c]   = sig(guess_[c])
// (round-5/6 version — measured best)
// ---------------------------------------------------------------------------
__global__ __launch_bounds__(256) void compute_q_kernel(
    const float* __restrict__ P, const float* __restrict__ D,
    const float* __restrict__ P_A, const float* __restrict__ P_B,
    const float* __restrict__ P_C, const float* __restrict__ D_A,
    const float* __restrict__ D_B, const float* __restrict__ guess_,
    const float* __restrict__ slide_,
    float* __restrict__ Q2, float* __restrict__ G)
{
    const int c    = blockIdx.x;
    const int t    = threadIdx.x;
    const int w    = t >> 6;
    const int lane = t & 63;            // == k

    __shared__ float PCs[BB * BB];
    __shared__ float rowsum_sh[KK];

    if (t < (BB * BB) / 4) ((float4*)PCs)[t] = ((const float4*)P_C)[t];

    {
        const int k = t >> 2, q = t & 3;
        const float* __restrict__ pr  = P   + k * CC + q * 25;
        const float* __restrict__ par = P_A + k * CC + q * 25;
        const float* __restrict__ pbr = P_B + k * CC + q * 25;
        float s = 0.f;
        #pragma unroll
        for (int i = 0; i < 25; ++i) s += __expf(fmaf(pr[i], par[i], pbr[i]));
        s += __shfl_xor(s, 1);
        s += __shfl_xor(s, 2);
        if (q == 0) rowsum_sh[k] = s;
    }

    float dm[BB];
    {
        const float4* d4  = (const float4*)(D   + lane * BB);
        const float4* da4 = (const float4*)(D_A + lane * BB);
        const float4* db4 = (const float4*)(D_B + lane * BB);
        #pragma unroll
        for (int i = 0; i < 5; ++i) {
            const float4 dv = d4[i], av = da4[i], bv = db4[i];
            dm[4 * i + 0] = __expf(fmaf(dv.x, av.x, bv.x));
            dm[4 * i + 1] = __expf(fmaf(dv.y, av.y, bv.y));
            dm[4 * i + 2] = __expf(fmaf(dv.z, av.z, bv.z));
            dm[4 * i + 3] = __expf(fmaf(dv.w, av.w, bv.w));
        }
    }
    #pragma unroll
    for (int b = 0; b < BB; ++b) {
        float s = dm[b];
        s += __shfl_xor(s, 1);  s += __shfl_xor(s, 2);  s += __shfl_xor(s, 4);
        s += __shfl_xor(s, 8);  s += __shfl_xor(s, 16); s += __shfl_xor(s, 32);
        dm[b] *= (1.f / s);
    }
    __syncthreads();

    float ev[5];
    #pragma unroll
    for (int j = 0; j < 5; ++j) {
        const int b = 5 * w + j;
        float acc = 0.f;
        #pragma unroll
        for (int jj = 0; jj < BB; ++jj) acc = fmaf(dm[jj], PCs[jj * BB + b], acc);
        ev[j] = acc;
    }

    const float ps = fmaf(P[lane * CC + c], P_A[lane * CC + c], P_B[lane * CC + c]);
    const float pm = __expf(ps) / rowsum_sh[lane];

    float qv[5];
    #pragma unroll
    for (int j = 0; j < 5; ++j) {
        float v = pm * ev[j];
        v += __shfl_xor(v, 1);  v += __shfl_xor(v, 2);  v += __shfl_xor(v, 4);
        v += __shfl_xor(v, 8);  v += __shfl_xor(v, 16); v += __shfl_xor(v, 32);
        qv[j] = v;
    }
    if (lane == 0) {
        const float g  = 1.f / (1.f + __expf(-guess_[c]));
        const float sl = 1.f / (1.f + __expf(-slide_[c]));
        const float scale = 1.f - sl - g;
        #pragma unroll
        for (int j = 0; j < 5; ++j) Q2[c * BB + 5 * w + j] = qv[j] * scale;
        if (w == 0) G[c] = g;
    }
}

// ---------------------------------------------------------------------------
// Kernel 2: round-6 measured-best variant (31.2 µs). Two samples per wave,
// no LDS, no barriers. Lane = b + 20*g, g<3 owns an L-chunk of column b for
// BOTH samples; both gathers issued up front; Q2/G register loads amortized
// across the two matvecs. Plain (L1-cached) loads — NT measured -10%,
// LDS staging measured -13%, col-pair dwordx2 measured -3%.
// ---------------------------------------------------------------------------
__global__ __launch_bounds__(256) void main_kernel(
    const float* __restrict__ X, const int* __restrict__ stu,
    const int* __restrict__ cour, const float* __restrict__ csa,
    const float* __restrict__ Q2, const float* __restrict__ G,
    float* __restrict__ out, int N)
{
    const int t = threadIdx.x;
    const int w = t >> 6, lane = t & 63;
    const int n0 = blockIdx.x * 8 + 2 * w;
    const int n1 = n0 + 1;
    if (n0 >= N) return;
    const bool hasB = (n1 < N);

    // Both samples' indices (wave-uniform scalar loads) and bases.
    const int sA = stu[n0], cA = cour[n0];
    const int sB = hasB ? stu[n1] : sA;
    const int cB = hasB ? cour[n1] : cA;
    const float* __restrict__ baseA = csa + ((size_t)sA * CC + cA) * (size_t)(LL * BB);
    const float* __restrict__ baseB = csa + ((size_t)sB * CC + cB) * (size_t)(LL * BB);

    const int b = lane % BB;
    const int g = lane / BB;                      // 0..3 (g3 mirrors g0, unused)
    const int l0 = (g >= 3) ? 0 : g * 17;
    const bool has17 = (g != 2);                  // g2 covers 16 rows

    // --- Issue both cold gathers first: 2 x (16+1) column loads. ---
    float va[16], vb[16];
    #pragma unroll
    for (int i = 0; i < 16; ++i) va[i] = baseA[(l0 + i) * BB + b];
    #pragma unroll
    for (int i = 0; i < 16; ++i) vb[i] = baseB[(l0 + i) * BB + b];
    float va16 = 0.f, vb16 = 0.f;
    if (has17) {
        va16 = baseA[(l0 + 16) * BB + b];
        vb16 = baseB[(l0 + 16) * BB + b];
    }

    // X rows: one coalesced load each, distributed by shuffle.
    const float xvA = (lane < LL) ? X[(size_t)n0 * LL + lane] : 0.f;
    const float xvB = (hasB && lane < LL) ? X[(size_t)n1 * LL + lane] : 0.f;

    // Hot operands (L1/L2): Q2 rows + G, shared by both samples.
    const int c1ok = (lane < CC - 64);
    float4 q0[5], q1[5];
    {
        const float4* Q2v0 = (const float4*)(Q2 + lane * BB);
        #pragma unroll
        for (int k = 0; k < 5; ++k) q0[k] = Q2v0[k];
        if (c1ok) {
            const float4* Q2v1 = (const float4*)(Q2 + (64 + lane) * BB);
            #pragma unroll
            for (int k = 0; k < 5; ++k) q1[k] = Q2v1[k];
        }
    }
    const float g0v = G[lane];
    const float g1v = c1ok ? G[64 + lane] : 0.f;

    // Fused column softmax + X-weighted reduce, both samples.
    float ssA = 0.f, tsA = 0.f, ssB = 0.f, tsB = 0.f;
    #pragma unroll
    for (int i = 0; i < 16; ++i) {
        const float eA = __expf(va[i]);
        const float eB = __expf(vb[i]);
        ssA += eA; ssB += eB;
        tsA = fmaf(eA, __shfl(xvA, l0 + i), tsA);
        tsB = fmaf(eB, __shfl(xvB, l0 + i), tsB);
    }
    if (has17) {
        const float eA = __expf(va16);
        const float eB = __expf(vb16);
        ssA += eA; ssB += eB;
        tsA = fmaf(eA, __shfl(xvA, l0 + 16), tsA);
        tsB = fmaf(eB, __shfl(xvB, l0 + 16), tsB);
    }

    // Combine 3 chunk partials per b for both samples.
    const float sTA = __shfl(ssA, b) + __shfl(ssA, b + BB) + __shfl(ssA, b + 2 * BB);
    const float tTA = __shfl(tsA, b) + __shfl(tsA, b + BB) + __shfl(tsA, b + 2 * BB);
    const float sTB = __shfl(ssB, b) + __shfl(ssB, b + BB) + __shfl(ssB, b + 2 * BB);
    const float tTB = __shfl(tsB, b) + __shfl(tsB, b + BB) + __shfl(tsB, b + 2 * BB);
    const float AvA = tTA / sTA;                  // lane j<20 holds A[n0][j]
    const float AvB = tTB / sTB;                  // lane j<20 holds A[n1][j]

    // Matvecs: out[n,c] = sum_b A[b]*Q2[c,b] + G[c], Q2 regs shared.
    float y0A = 0.f, y1A = 0.f, y0B = 0.f, y1B = 0.f;
    #pragma unroll
    for (int bb = 0; bb < BB; ++bb) {
        const float aA = __uint_as_float(
            __builtin_amdgcn_readlane(__float_as_uint(AvA), bb));
        const float aB = __uint_as_float(
            __builtin_amdgcn_readlane(__float_as_uint(AvB), bb));
        const float qv0 = ((const float*)q0)[bb];
        const float qv1 = ((const float*)q1)[bb];
        y0A = fmaf(aA, qv0, y0A);  y1A = fmaf(aA, qv1, y1A);
        y0B = fmaf(aB, qv0, y0B);  y1B = fmaf(aB, qv1, y1B);
    }
    float* orowA = out + (size_t)n0 * CC;
    orowA[lane] = y0A + g0v;
    if (c1ok) orowA[64 + lane] = y1A + g1v;
    if (hasB) {
        float* orowB = out + (size_t)n1 * CC;
        orowB[lane] = y0B + g0v;
        if (c1ok) orowB[64 + lane] = y1B + g1v;
    }
}

extern "C" void kernel_launch(void* const* d_in, const int* in_sizes, int n_in,
                              void* d_out, int out_size, void* d_ws, size_t ws_size,
                              hipStream_t stream) {
    const float* X      = (const float*)d_in[0];
    const int*   stu    = (const int*)  d_in[1];
    const int*   cour   = (const int*)  d_in[2];
    const float* csa    = (const float*)d_in[3];
    const float* P      = (const float*)d_in[4];
    const float* D      = (const float*)d_in[5];
    const float* P_A    = (const float*)d_in[6];
    const float* P_B    = (const float*)d_in[7];
    const float* P_C    = (const float*)d_in[8];
    const float* D_A    = (const float*)d_in[9];
    const float* D_B    = (const float*)d_in[10];
    const float* guess_ = (const float*)d_in[11];
    const float* slide_ = (const float*)d_in[12];
    float* out = (float*)d_out;
    float* Q2  = (float*)d_ws;            // C*B floats
    float* G   = (float*)d_ws + CC * BB;  // C floats

    const int N = in_sizes[1];   // 16384

    compute_q_kernel<<<CC, 256, 0, stream>>>(P, D, P_A, P_B, P_C, D_A, D_B,
                                             guess_, slide_, Q2, G);
    main_kernel<<<(N + 7) / 8, 256, 0, stream>>>(X, stu, cour, csa, Q2, G, out, N);
}